// Round 4
// baseline (3170.959 us; speedup 1.0000x reference)
//
#include <hip/hip_runtime.h>

#define E_EDGES   800000
#define HIDN      128
#define EDIMN     32
#define TILE      256                 // edges per block-iteration (8 waves x 32)
#define NT        (E_EDGES / TILE)    // 3125
#define GRID_MAIN 256

typedef __attribute__((ext_vector_type(8))) short bf16x8;
typedef __attribute__((ext_vector_type(4))) float f32x4;

static __device__ __forceinline__ unsigned short f2bf(float f) {
  unsigned int u = __float_as_uint(f);
  u += 0x7fffu + ((u >> 16) & 1u);
  return (unsigned short)(u >> 16);
}
// pack two floats as bf16 pair into u32 (pure C)
static __device__ __forceinline__ unsigned int pk2c(float a, float b) {
  return (unsigned int)f2bf(a) | (((unsigned int)f2bf(b)) << 16);
}
// expand packed bf16 pair back to two f32 (exact)
static __device__ __forceinline__ f32x4 bini(unsigned int u0, unsigned int u1) {
  f32x4 r;
  r[0] = __uint_as_float(u0 << 16);
  r[1] = __uint_as_float(u0 & 0xffff0000u);
  r[2] = __uint_as_float(u1 << 16);
  r[3] = __uint_as_float(u1 & 0xffff0000u);
  return r;
}
// swizzles (XOR within 16B granules; kElem multiple of 8 stays granule-aligned)
static __device__ __forceinline__ int swz(int row, int kElem) {
  return row * HIDN + (kElem ^ ((row & 7) << 3));
}
static __device__ __forceinline__ int swz32(int row, int kElem) {
  return row * EDIMN + (kElem ^ ((row & 3) << 3));
}
// k-permutation: hardware slot k_hw holds logical k = nmap(k_hw) (bit permutation, bijective)
static __device__ __forceinline__ int nmap(int k) {
  return ((k >> 5) << 5) | (((k & 7) >> 2) << 4) | (((k >> 3) & 3) << 2) | (k & 3);
}

template <bool RELU>
static __device__ __forceinline__ void packB(const f32x4* acc, bf16x8* B) {
#pragma unroll
  for (int ks = 0; ks < 4; ++ks) {
    f32x4 a = acc[2 * ks], b = acc[2 * ks + 1];
    if (RELU) {
#pragma unroll
      for (int j = 0; j < 4; ++j) { a[j] = fmaxf(a[j], 0.f); b[j] = fmaxf(b[j], 0.f); }
    }
    bf16x8 v;
    v[0] = (short)f2bf(a[0]); v[1] = (short)f2bf(a[1]);
    v[2] = (short)f2bf(a[2]); v[3] = (short)f2bf(a[3]);
    v[4] = (short)f2bf(b[0]); v[5] = (short)f2bf(b[1]);
    v[6] = (short)f2bf(b[2]); v[7] = (short)f2bf(b[3]);
    B[ks] = v;
  }
}

static __device__ __forceinline__ void mmT(const unsigned short* W, f32x4* a0, f32x4* a1,
                                           const bf16x8* B0, const bf16x8* B1,
                                           int c16, int q) {
#pragma unroll
  for (int cb = 0; cb < 8; ++cb) {
#pragma unroll
    for (int ks = 0; ks < 4; ++ks) {
      bf16x8 w = *reinterpret_cast<const bf16x8*>(&W[swz(cb * 16 + c16, ks * 32 + q * 8)]);
      a0[cb] = __builtin_amdgcn_mfma_f32_16x16x32_bf16(w, B0[ks], a0[cb], 0, 0, 0);
      a1[cb] = __builtin_amdgcn_mfma_f32_16x16x32_bf16(w, B1[ks], a1[cb], 0, 0, 0);
    }
  }
}

__global__ void k_detect(const int* __restrict__ ei, int* __restrict__ flag) {
  __shared__ int nz;
  if (threadIdx.x == 0) nz = 0;
  __syncthreads();
  if (ei[2 * threadIdx.x + 1] != 0) atomicAdd(&nz, 1);
  __syncthreads();
  if (threadIdx.x == 0) flag[0] = (nz == 0) ? 1 : 0;   // 1 => int64
}

__global__ void k_norm(const int* __restrict__ ei, const int* __restrict__ flag,
                       int* __restrict__ idx) {
  const int stride = gridDim.x * blockDim.x;
  const int w = flag[0];
  for (int i = blockIdx.x * blockDim.x + threadIdx.x; i < 2 * E_EDGES; i += stride)
    idx[i] = w ? ei[2 * i] : ei[i];
}

__launch_bounds__(512, 1)
__global__ void k_conv(const float* __restrict__ x, const float* __restrict__ ea,
                       const int* __restrict__ gidx, const int* __restrict__ sidx,
                       const float* __restrict__ We1, const float* __restrict__ be1,
                       const float* __restrict__ We2, const float* __restrict__ be2,
                       const float* __restrict__ Wm1, const float* __restrict__ bm1,
                       const float* __restrict__ Wm2, const float* __restrict__ bm2,
                       const float* __restrict__ alphap, int dir,
                       float* __restrict__ out) {
  __shared__ unsigned short wt[3][HIDN * HIDN];   // We2,Wm1,Wm2*scale; [n][k_hw] swizzled, 96KB
  __shared__ unsigned short w1[HIDN * EDIMN];     // We1^T [n][k], 8KB
  __shared__ float b3eff[HIDN];                   // bm1 + be2 @ Wm1

  const int tid = threadIdx.x;
  const int wv  = tid >> 6;
  const int ln  = tid & 63;
  const int q   = ln >> 4;
  const int c16 = ln & 15;

  const float sg    = 1.f / (1.f + expf(-alphap[0]));
  const float scale = dir ? (1.f - sg) : sg;

  {  // stage weights with k-permutation (coalesced over n)
    const float* Ws[3] = {We2, Wm1, Wm2};
    for (int m = 0; m < 3; ++m) {
      const float s = (m == 2) ? scale : 1.f;
      const float* W = Ws[m];
      for (int p = tid; p < HIDN * HIDN; p += 512) {
        int n = p & (HIDN - 1), k = p >> 7;
        wt[m][swz(n, k)] = f2bf(W[nmap(k) * HIDN + n] * s);
      }
    }
    for (int p = tid; p < HIDN * EDIMN; p += 512) {
      int n = p & (HIDN - 1), k = p >> 7;
      w1[swz32(n, k)] = f2bf(We1[k * HIDN + n]);
    }
    for (int n = tid; n < HIDN; n += 512) {  // fold be2 into stage-3 bias
      float acc = bm1[n];
      for (int k = 0; k < HIDN; ++k) acc += be2[k] * Wm1[k * HIDN + n];
      b3eff[n] = acc;
    }
  }
  __syncthreads();

  // biases, bf16-pair-packed in registers: acc slot [cb][j] is feature n = 16cb+4q+j
  unsigned int vbA[8][2], vbC[8][2], vbD[8][2];
#pragma unroll
  for (int cb = 0; cb < 8; ++cb) {
    int o = cb * 16 + q * 4;
    vbA[cb][0] = pk2c(be1[o], be1[o + 1]);
    vbA[cb][1] = pk2c(be1[o + 2], be1[o + 3]);
    vbC[cb][0] = pk2c(b3eff[o], b3eff[o + 1]);
    vbC[cb][1] = pk2c(b3eff[o + 2], b3eff[o + 3]);
    vbD[cb][0] = pk2c(bm2[o] * scale, bm2[o + 1] * scale);
    vbD[cb][1] = pk2c(bm2[o + 2] * scale, bm2[o + 3] * scale);
  }

  for (int t = blockIdx.x; t < NT; t += GRID_MAIN) {
    const int e_ = t * TILE + wv * 32 + c16;

    // edge-attr rows for this lane's two edges (e_, e_+16)
    f32x4 e0a = *reinterpret_cast<const f32x4*>(&ea[(size_t)e_ * EDIMN + q * 8]);
    f32x4 e0b = *reinterpret_cast<const f32x4*>(&ea[(size_t)e_ * EDIMN + q * 8 + 4]);
    f32x4 e1a = *reinterpret_cast<const f32x4*>(&ea[(size_t)(e_ + 16) * EDIMN + q * 8]);
    f32x4 e1b = *reinterpret_cast<const f32x4*>(&ea[(size_t)(e_ + 16) * EDIMN + q * 8 + 4]);
    const int gi0 = gidx[e_], gi1 = gidx[e_ + 16];
    const int si0 = sidx[e_], si1 = sidx[e_ + 16];

    // x-gather for stage-2 acc init (issued early, consumed after stage 1)
    f32x4 xg0[8], xg1[8];
#pragma unroll
    for (int cb = 0; cb < 8; ++cb) {
      xg0[cb] = *reinterpret_cast<const f32x4*>(&x[(size_t)gi0 * HIDN + cb * 16 + q * 4]);
      xg1[cb] = *reinterpret_cast<const f32x4*>(&x[(size_t)gi1 * HIDN + cb * 16 + q * 4]);
    }

    f32x4 A0[8], A1[8];
    bf16x8 B0[4], B1[4];

    // ---- stage 1: relu(ea @ We1 + be1)   (K=32, natural k order)
    {
      bf16x8 E0, E1;
      E0[0] = (short)f2bf(e0a[0]); E0[1] = (short)f2bf(e0a[1]);
      E0[2] = (short)f2bf(e0a[2]); E0[3] = (short)f2bf(e0a[3]);
      E0[4] = (short)f2bf(e0b[0]); E0[5] = (short)f2bf(e0b[1]);
      E0[6] = (short)f2bf(e0b[2]); E0[7] = (short)f2bf(e0b[3]);
      E1[0] = (short)f2bf(e1a[0]); E1[1] = (short)f2bf(e1a[1]);
      E1[2] = (short)f2bf(e1a[2]); E1[3] = (short)f2bf(e1a[3]);
      E1[4] = (short)f2bf(e1b[0]); E1[5] = (short)f2bf(e1b[1]);
      E1[6] = (short)f2bf(e1b[2]); E1[7] = (short)f2bf(e1b[3]);
#pragma unroll
      for (int cb = 0; cb < 8; ++cb) {
        A0[cb] = bini(vbA[cb][0], vbA[cb][1]);
        A1[cb] = A0[cb];
      }
#pragma unroll
      for (int cb = 0; cb < 8; ++cb) {
        bf16x8 w = *reinterpret_cast<const bf16x8*>(&w1[swz32(cb * 16 + c16, q * 8)]);
        A0[cb] = __builtin_amdgcn_mfma_f32_16x16x32_bf16(w, E0, A0[cb], 0, 0, 0);
        A1[cb] = __builtin_amdgcn_mfma_f32_16x16x32_bf16(w, E1, A1[cb], 0, 0, 0);
      }
      packB<true>(A0, B0);
      packB<true>(A1, B1);
    }

    // ---- stage 2: Y1 @ We2 + x[g]  (be2 folded into stage-3 bias)
#pragma unroll
    for (int cb = 0; cb < 8; ++cb) { A0[cb] = xg0[cb]; A1[cb] = xg1[cb]; }
    mmT(&wt[0][0], A0, A1, B0, B1, c16, q);
    packB<false>(A0, B0);
    packB<false>(A1, B1);

    // ---- stage 3: relu(. @ Wm1 + b3eff)
#pragma unroll
    for (int cb = 0; cb < 8; ++cb) {
      A0[cb] = bini(vbC[cb][0], vbC[cb][1]);
      A1[cb] = A0[cb];
    }
    mmT(&wt[1][0], A0, A1, B0, B1, c16, q);
    packB<true>(A0, B0);
    packB<true>(A1, B1);

    // ---- stage 4: . @ (Wm2*scale) + bm2*scale ; atomic scatter
#pragma unroll
    for (int cb = 0; cb < 8; ++cb) {
      A0[cb] = bini(vbD[cb][0], vbD[cb][1]);
      A1[cb] = A0[cb];
    }
    mmT(&wt[2][0], A0, A1, B0, B1, c16, q);
#pragma unroll
    for (int cb = 0; cb < 8; ++cb) {
      float* p0 = out + (size_t)si0 * HIDN + cb * 16 + q * 4;
      float* p1 = out + (size_t)si1 * HIDN + cb * 16 + q * 4;
#pragma unroll
      for (int j = 0; j < 4; ++j) {
        unsafeAtomicAdd(p0 + j, A0[cb][j]);
        unsafeAtomicAdd(p1 + j, A1[cb][j]);
      }
    }
  }
}

extern "C" void kernel_launch(void* const* d_in, const int* in_sizes, int n_in,
                              void* d_out, int out_size, void* d_ws, size_t ws_size,
                              hipStream_t stream) {
  const float* x     = (const float*)d_in[0];
  const int*   ei    = (const int*)d_in[1];
  const float* ea    = (const float*)d_in[2];
  const float* alpha = (const float*)d_in[3];
  const float* fWe1 = (const float*)d_in[4],  *fbe1 = (const float*)d_in[5];
  const float* fWe2 = (const float*)d_in[6],  *fbe2 = (const float*)d_in[7];
  const float* fWm1 = (const float*)d_in[8],  *fbm1 = (const float*)d_in[9];
  const float* fWm2 = (const float*)d_in[10], *fbm2 = (const float*)d_in[11];
  const float* bWe1 = (const float*)d_in[12], *bbe1 = (const float*)d_in[13];
  const float* bWe2 = (const float*)d_in[14], *bbe2 = (const float*)d_in[15];
  const float* bWm1 = (const float*)d_in[16], *bbm1 = (const float*)d_in[17];
  const float* bWm2 = (const float*)d_in[18], *bbm2 = (const float*)d_in[19];
  float* out = (float*)d_out;

  int* flag = (int*)d_ws;
  int* idx  = (int*)((char*)d_ws + 256);   // 2*E int32
  int* srcI = idx;
  int* dstI = idx + E_EDGES;

  hipMemsetAsync(d_out, 0, (size_t)out_size * sizeof(float), stream);
  k_detect<<<1, 256, 0, stream>>>(ei, flag);
  k_norm<<<2048, 256, 0, stream>>>(ei, flag, idx);

  // forward: gather x[src], scatter to dst, weight sigma(alpha)
  k_conv<<<GRID_MAIN, 512, 0, stream>>>(x, ea, srcI, dstI,
                                        fWe1, fbe1, fWe2, fbe2, fWm1, fbm1, fWm2, fbm2,
                                        alpha, 0, out);
  // backward: gather x[dst], scatter to src, weight 1-sigma(alpha)
  k_conv<<<GRID_MAIN, 512, 0, stream>>>(x, ea, dstI, srcI,
                                        bWe1, bbe1, bWe2, bbe2, bWm1, bbm1, bWm2, bbm2,
                                        alpha, 1, out);
}

// Round 5
// 1418.839 us; speedup vs baseline: 2.2349x; 2.2349x over previous
//
#include <hip/hip_runtime.h>

#define E_EDGES   800000
#define HIDN      128
#define EDIMN     32
#define TILE      256                 // edges per block-iteration (8 waves x 32)
#define NT        (E_EDGES / TILE)    // 3125
#define GRID_MAIN 256
#define STR       35                  // stg row stride (f32): odd-ish -> rows spread banks

typedef __attribute__((ext_vector_type(8))) short bf16x8;
typedef __attribute__((ext_vector_type(4))) float f32x4;

static __device__ __forceinline__ unsigned short f2bf(float f) {
  unsigned int u = __float_as_uint(f);
  u += 0x7fffu + ((u >> 16) & 1u);
  return (unsigned short)(u >> 16);
}
static __device__ __forceinline__ unsigned int pk2c(float a, float b) {
  return (unsigned int)f2bf(a) | (((unsigned int)f2bf(b)) << 16);
}
static __device__ __forceinline__ f32x4 bini(unsigned int u0, unsigned int u1) {
  f32x4 r;
  r[0] = __uint_as_float(u0 << 16);
  r[1] = __uint_as_float(u0 & 0xffff0000u);
  r[2] = __uint_as_float(u1 << 16);
  r[3] = __uint_as_float(u1 & 0xffff0000u);
  return r;
}
static __device__ __forceinline__ int swz(int row, int kElem) {
  return row * HIDN + (kElem ^ ((row & 7) << 3));
}
// k-permutation: hardware slot k_hw holds logical k = nmap(k_hw) (bit permutation, bijective)
static __device__ __forceinline__ int nmap(int k) {
  return ((k >> 5) << 5) | (((k & 7) >> 2) << 4) | (((k >> 3) & 3) << 2) | (k & 3);
}

template <bool RELU>
static __device__ __forceinline__ void packB(const f32x4* acc, bf16x8* B) {
#pragma unroll
  for (int ks = 0; ks < 4; ++ks) {
    f32x4 a = acc[2 * ks], b = acc[2 * ks + 1];
    if (RELU) {
#pragma unroll
      for (int j = 0; j < 4; ++j) { a[j] = fmaxf(a[j], 0.f); b[j] = fmaxf(b[j], 0.f); }
    }
    bf16x8 v;
    v[0] = (short)f2bf(a[0]); v[1] = (short)f2bf(a[1]);
    v[2] = (short)f2bf(a[2]); v[3] = (short)f2bf(a[3]);
    v[4] = (short)f2bf(b[0]); v[5] = (short)f2bf(b[1]);
    v[6] = (short)f2bf(b[2]); v[7] = (short)f2bf(b[3]);
    B[ks] = v;
  }
}

static __device__ __forceinline__ void mmT(const unsigned short* W, f32x4* a0, f32x4* a1,
                                           const bf16x8* B0, const bf16x8* B1,
                                           int c16, int q) {
#pragma unroll
  for (int cb = 0; cb < 8; ++cb) {
#pragma unroll
    for (int ks = 0; ks < 4; ++ks) {
      bf16x8 w = *reinterpret_cast<const bf16x8*>(&W[swz(cb * 16 + c16, ks * 32 + q * 8)]);
      a0[cb] = __builtin_amdgcn_mfma_f32_16x16x32_bf16(w, B0[ks], a0[cb], 0, 0, 0);
      a1[cb] = __builtin_amdgcn_mfma_f32_16x16x32_bf16(w, B1[ks], a1[cb], 0, 0, 0);
    }
  }
}

__global__ void k_detect(const int* __restrict__ ei, int* __restrict__ flag) {
  __shared__ int nz;
  if (threadIdx.x == 0) nz = 0;
  __syncthreads();
  if (ei[2 * threadIdx.x + 1] != 0) atomicAdd(&nz, 1);
  __syncthreads();
  if (threadIdx.x == 0) flag[0] = (nz == 0) ? 1 : 0;   // 1 => int64
}

__global__ void k_norm(const int* __restrict__ ei, const int* __restrict__ flag,
                       int* __restrict__ idx) {
  const int stride = gridDim.x * blockDim.x;
  const int w = flag[0];
  for (int i = blockIdx.x * blockDim.x + threadIdx.x; i < 2 * E_EDGES; i += stride)
    idx[i] = w ? ei[2 * i] : ei[i];
}

__launch_bounds__(512, 1)
__global__ void k_conv(const float* __restrict__ x, const float* __restrict__ ea,
                       const int* __restrict__ gidx, const int* __restrict__ sidx,
                       const float* __restrict__ We1, const float* __restrict__ be1,
                       const float* __restrict__ We2, const float* __restrict__ be2,
                       const float* __restrict__ Wm1, const float* __restrict__ bm1,
                       const float* __restrict__ Wm2, const float* __restrict__ bm2,
                       const float* __restrict__ alphap, int dir,
                       float* __restrict__ out) {
  __shared__ unsigned short wt[3][HIDN * HIDN];   // We2,Wm1,Wm2*scale; [n][k_hw] swizzled, 96KB
  __shared__ float stg[8][32][STR];               // per-wave epilogue transpose, 35840B
  __shared__ float b3eff[HIDN];                   // bm1 + be2 @ Wm1

  const int tid = threadIdx.x;
  const int wv  = tid >> 6;
  const int ln  = tid & 63;
  const int q   = ln >> 4;
  const int c16 = ln & 15;

  const float sg    = 1.f / (1.f + expf(-alphap[0]));
  const float scale = dir ? (1.f - sg) : sg;

  {  // stage weights with k-permutation (coalesced over n)
    const float* Ws[3] = {We2, Wm1, Wm2};
    for (int m = 0; m < 3; ++m) {
      const float s = (m == 2) ? scale : 1.f;
      const float* W = Ws[m];
      for (int p = tid; p < HIDN * HIDN; p += 512) {
        int n = p & (HIDN - 1), k = p >> 7;
        wt[m][swz(n, k)] = f2bf(W[nmap(k) * HIDN + n] * s);
      }
    }
    for (int n = tid; n < HIDN; n += 512) {  // fold be2 into stage-3 bias
      float acc = bm1[n];
      for (int k = 0; k < HIDN; ++k) acc += be2[k] * Wm1[k * HIDN + n];
      b3eff[n] = acc;
    }
  }
  __syncthreads();

  // We1^T A-fragments in registers: fw1[cb][j] = We1[(q*8+j)*128 + cb*16+c16]
  bf16x8 fw1[8];
#pragma unroll
  for (int cb = 0; cb < 8; ++cb)
#pragma unroll
    for (int j = 0; j < 8; ++j)
      fw1[cb][j] = (short)f2bf(We1[(q * 8 + j) * HIDN + cb * 16 + c16]);

  // biases, bf16-pair-packed in registers: acc slot [cb][j] is feature n = 16cb+4q+j
  unsigned int vbA[8][2], vbC[8][2], vbD[8][2];
#pragma unroll
  for (int cb = 0; cb < 8; ++cb) {
    int o = cb * 16 + q * 4;
    vbA[cb][0] = pk2c(be1[o], be1[o + 1]);
    vbA[cb][1] = pk2c(be1[o + 2], be1[o + 3]);
    vbC[cb][0] = pk2c(b3eff[o], b3eff[o + 1]);
    vbC[cb][1] = pk2c(b3eff[o + 2], b3eff[o + 3]);
    vbD[cb][0] = pk2c(bm2[o] * scale, bm2[o + 1] * scale);
    vbD[cb][1] = pk2c(bm2[o + 2] * scale, bm2[o + 3] * scale);
  }

  for (int t = blockIdx.x; t < NT; t += GRID_MAIN) {
    const int e0w = t * TILE + wv * 32;
    const int e_  = e0w + c16;

    f32x4 e0a = *reinterpret_cast<const f32x4*>(&ea[(size_t)e_ * EDIMN + q * 8]);
    f32x4 e0b = *reinterpret_cast<const f32x4*>(&ea[(size_t)e_ * EDIMN + q * 8 + 4]);
    f32x4 e1a = *reinterpret_cast<const f32x4*>(&ea[(size_t)(e_ + 16) * EDIMN + q * 8]);
    f32x4 e1b = *reinterpret_cast<const f32x4*>(&ea[(size_t)(e_ + 16) * EDIMN + q * 8 + 4]);
    const int gi0 = gidx[e_], gi1 = gidx[e_ + 16];

    // scatter indices for the epilogue's row orientation (rows r = 16mb+4q+j)
    int sir[2][4];
#pragma unroll
    for (int mb = 0; mb < 2; ++mb)
#pragma unroll
      for (int j = 0; j < 4; ++j)
        sir[mb][j] = sidx[e0w + 16 * mb + 4 * q + j];

    // x-gather for stage-2 acc init
    f32x4 xg0[8], xg1[8];
#pragma unroll
    for (int cb = 0; cb < 8; ++cb) {
      xg0[cb] = *reinterpret_cast<const f32x4*>(&x[(size_t)gi0 * HIDN + cb * 16 + q * 4]);
      xg1[cb] = *reinterpret_cast<const f32x4*>(&x[(size_t)gi1 * HIDN + cb * 16 + q * 4]);
    }

    f32x4 A0[8], A1[8];
    bf16x8 B0[4], B1[4];

    // ---- stage 1: relu(ea @ We1 + be1)
    {
      bf16x8 E0, E1;
      E0[0] = (short)f2bf(e0a[0]); E0[1] = (short)f2bf(e0a[1]);
      E0[2] = (short)f2bf(e0a[2]); E0[3] = (short)f2bf(e0a[3]);
      E0[4] = (short)f2bf(e0b[0]); E0[5] = (short)f2bf(e0b[1]);
      E0[6] = (short)f2bf(e0b[2]); E0[7] = (short)f2bf(e0b[3]);
      E1[0] = (short)f2bf(e1a[0]); E1[1] = (short)f2bf(e1a[1]);
      E1[2] = (short)f2bf(e1a[2]); E1[3] = (short)f2bf(e1a[3]);
      E1[4] = (short)f2bf(e1b[0]); E1[5] = (short)f2bf(e1b[1]);
      E1[6] = (short)f2bf(e1b[2]); E1[7] = (short)f2bf(e1b[3]);
#pragma unroll
      for (int cb = 0; cb < 8; ++cb) {
        A0[cb] = bini(vbA[cb][0], vbA[cb][1]);
        A1[cb] = A0[cb];
      }
#pragma unroll
      for (int cb = 0; cb < 8; ++cb) {
        A0[cb] = __builtin_amdgcn_mfma_f32_16x16x32_bf16(fw1[cb], E0, A0[cb], 0, 0, 0);
        A1[cb] = __builtin_amdgcn_mfma_f32_16x16x32_bf16(fw1[cb], E1, A1[cb], 0, 0, 0);
      }
      packB<true>(A0, B0);
      packB<true>(A1, B1);
    }

    // ---- stage 2: Y1 @ We2 + x[g]  (be2 folded into stage-3 bias)
#pragma unroll
    for (int cb = 0; cb < 8; ++cb) { A0[cb] = xg0[cb]; A1[cb] = xg1[cb]; }
    mmT(&wt[0][0], A0, A1, B0, B1, c16, q);
    packB<false>(A0, B0);
    packB<false>(A1, B1);

    // ---- stage 3: relu(. @ Wm1 + b3eff)
#pragma unroll
    for (int cb = 0; cb < 8; ++cb) {
      A0[cb] = bini(vbC[cb][0], vbC[cb][1]);
      A1[cb] = A0[cb];
    }
    mmT(&wt[1][0], A0, A1, B0, B1, c16, q);
    packB<true>(A0, B0);
    packB<true>(A1, B1);

    // ---- stage 4: . @ (Wm2*scale) + bm2*scale
#pragma unroll
    for (int cb = 0; cb < 8; ++cb) {
      A0[cb] = bini(vbD[cb][0], vbD[cb][1]);
      A1[cb] = A0[cb];
    }
    mmT(&wt[2][0], A0, A1, B0, B1, c16, q);

    // ---- epilogue: per-wave LDS transpose -> full-line atomics
    // 4 passes of 32 feature-cols; storage col perm: feature 16c+4q+j stored at 16c+q+4j
#pragma unroll
    for (int p = 0; p < 4; ++p) {
#pragma unroll
      for (int cb2 = 0; cb2 < 2; ++cb2) {
        const int cb = 2 * p + cb2;
#pragma unroll
        for (int j = 0; j < 4; ++j) {
          stg[wv][c16][16 * cb2 + q + 4 * j]      = A0[cb][j];
          stg[wv][c16 + 16][16 * cb2 + q + 4 * j] = A1[cb][j];
        }
      }
      const int ca = c16 >> 2, cbt = c16 & 3;      // read perm: col C=16k+c16 -> 16k+4*cbt+ca
#pragma unroll
      for (int mb = 0; mb < 2; ++mb)
#pragma unroll
        for (int j = 0; j < 4; ++j) {
          const int r = 16 * mb + 4 * q + j;
          float v0 = stg[wv][r][4 * cbt + ca];
          float v1 = stg[wv][r][16 + 4 * cbt + ca];
          float* po = out + (size_t)sir[mb][j] * HIDN + 32 * p + c16;
          unsafeAtomicAdd(po, v0);
          unsafeAtomicAdd(po + 16, v1);
        }
    }
  }
}

extern "C" void kernel_launch(void* const* d_in, const int* in_sizes, int n_in,
                              void* d_out, int out_size, void* d_ws, size_t ws_size,
                              hipStream_t stream) {
  const float* x     = (const float*)d_in[0];
  const int*   ei    = (const int*)d_in[1];
  const float* ea    = (const float*)d_in[2];
  const float* alpha = (const float*)d_in[3];
  const float* fWe1 = (const float*)d_in[4],  *fbe1 = (const float*)d_in[5];
  const float* fWe2 = (const float*)d_in[6],  *fbe2 = (const float*)d_in[7];
  const float* fWm1 = (const float*)d_in[8],  *fbm1 = (const float*)d_in[9];
  const float* fWm2 = (const float*)d_in[10], *fbm2 = (const float*)d_in[11];
  const float* bWe1 = (const float*)d_in[12], *bbe1 = (const float*)d_in[13];
  const float* bWe2 = (const float*)d_in[14], *bbe2 = (const float*)d_in[15];
  const float* bWm1 = (const float*)d_in[16], *bbm1 = (const float*)d_in[17];
  const float* bWm2 = (const float*)d_in[18], *bbm2 = (const float*)d_in[19];
  float* out = (float*)d_out;

  int* flag = (int*)d_ws;
  int* idx  = (int*)((char*)d_ws + 256);   // 2*E int32
  int* srcI = idx;
  int* dstI = idx + E_EDGES;

  hipMemsetAsync(d_out, 0, (size_t)out_size * sizeof(float), stream);
  k_detect<<<1, 256, 0, stream>>>(ei, flag);
  k_norm<<<2048, 256, 0, stream>>>(ei, flag, idx);

  // forward: gather x[src], scatter to dst, weight sigma(alpha)
  k_conv<<<GRID_MAIN, 512, 0, stream>>>(x, ea, srcI, dstI,
                                        fWe1, fbe1, fWe2, fbe2, fWm1, fbm1, fWm2, fbm2,
                                        alpha, 0, out);
  // backward: gather x[dst], scatter to src, weight 1-sigma(alpha)
  k_conv<<<GRID_MAIN, 512, 0, stream>>>(x, ea, dstI, srcI,
                                        bWe1, bbe1, bWe2, bbe2, bWm1, bbm1, bWm2, bbm2,
                                        alpha, 1, out);
}

// Round 6
// 1408.897 us; speedup vs baseline: 2.2507x; 1.0071x over previous
//
#include <hip/hip_runtime.h>

#define E_EDGES   800000
#define HIDN      128
#define EDIMN     32
#define TILE      256                 // edges per block-iteration (8 waves x 32)
#define NT        (E_EDGES / TILE)    // 3125
#define GRID_MAIN 256
#define STR       35                  // stg row stride (f32): odd-ish -> rows spread banks

typedef __attribute__((ext_vector_type(8))) short bf16x8;
typedef __attribute__((ext_vector_type(4))) float f32x4;

static __device__ __forceinline__ unsigned short f2bf(float f) {
  unsigned int u = __float_as_uint(f);
  u += 0x7fffu + ((u >> 16) & 1u);
  return (unsigned short)(u >> 16);
}
static __device__ __forceinline__ unsigned int pk2c(float a, float b) {
  return (unsigned int)f2bf(a) | (((unsigned int)f2bf(b)) << 16);
}
static __device__ __forceinline__ f32x4 bini(unsigned int u0, unsigned int u1) {
  f32x4 r;
  r[0] = __uint_as_float(u0 << 16);
  r[1] = __uint_as_float(u0 & 0xffff0000u);
  r[2] = __uint_as_float(u1 << 16);
  r[3] = __uint_as_float(u1 & 0xffff0000u);
  return r;
}
static __device__ __forceinline__ int swz(int row, int kElem) {
  return row * HIDN + (kElem ^ ((row & 7) << 3));
}
// k-permutation: hardware slot k_hw holds logical k = nmap(k_hw) (bit permutation, bijective)
static __device__ __forceinline__ int nmap(int k) {
  return ((k >> 5) << 5) | (((k & 7) >> 2) << 4) | (((k >> 3) & 3) << 2) | (k & 3);
}

template <bool RELU>
static __device__ __forceinline__ void packB(const f32x4* acc, bf16x8* B) {
#pragma unroll
  for (int ks = 0; ks < 4; ++ks) {
    f32x4 a = acc[2 * ks], b = acc[2 * ks + 1];
    if (RELU) {
#pragma unroll
      for (int j = 0; j < 4; ++j) { a[j] = fmaxf(a[j], 0.f); b[j] = fmaxf(b[j], 0.f); }
    }
    bf16x8 v;
    v[0] = (short)f2bf(a[0]); v[1] = (short)f2bf(a[1]);
    v[2] = (short)f2bf(a[2]); v[3] = (short)f2bf(a[3]);
    v[4] = (short)f2bf(b[0]); v[5] = (short)f2bf(b[1]);
    v[6] = (short)f2bf(b[2]); v[7] = (short)f2bf(b[3]);
    B[ks] = v;
  }
}

static __device__ __forceinline__ void mmT(const unsigned short* W, f32x4* a0, f32x4* a1,
                                           const bf16x8* B0, const bf16x8* B1,
                                           int c16, int q) {
#pragma unroll
  for (int cb = 0; cb < 8; ++cb) {
#pragma unroll
    for (int ks = 0; ks < 4; ++ks) {
      bf16x8 w = *reinterpret_cast<const bf16x8*>(&W[swz(cb * 16 + c16, ks * 32 + q * 8)]);
      a0[cb] = __builtin_amdgcn_mfma_f32_16x16x32_bf16(w, B0[ks], a0[cb], 0, 0, 0);
      a1[cb] = __builtin_amdgcn_mfma_f32_16x16x32_bf16(w, B1[ks], a1[cb], 0, 0, 0);
    }
  }
}

__global__ void k_detect(const int* __restrict__ ei, int* __restrict__ flag) {
  __shared__ int nz;
  if (threadIdx.x == 0) nz = 0;
  __syncthreads();
  if (ei[2 * threadIdx.x + 1] != 0) atomicAdd(&nz, 1);
  __syncthreads();
  if (threadIdx.x == 0) flag[0] = (nz == 0) ? 1 : 0;   // 1 => int64
}

__global__ void k_norm(const int* __restrict__ ei, const int* __restrict__ flag,
                       int* __restrict__ idx) {
  const int stride = gridDim.x * blockDim.x;
  const int w = flag[0];
  for (int i = blockIdx.x * blockDim.x + threadIdx.x; i < 2 * E_EDGES; i += stride)
    idx[i] = w ? ei[2 * i] : ei[i];
}

__launch_bounds__(512)
__global__ void k_conv(const float* __restrict__ x, const float* __restrict__ ea,
                       const int* __restrict__ gidx, const int* __restrict__ sidx,
                       const float* __restrict__ We1, const float* __restrict__ be1,
                       const float* __restrict__ We2, const float* __restrict__ be2,
                       const float* __restrict__ Wm1, const float* __restrict__ bm1,
                       const float* __restrict__ Wm2, const float* __restrict__ bm2,
                       const float* __restrict__ alphap, int dir,
                       float* __restrict__ out) {
  __shared__ unsigned short wt[3][HIDN * HIDN];   // We2,Wm1,Wm2*scale; [n][k_hw] swizzled, 96KB
  __shared__ float stg[8][32][STR];               // per-wave epilogue transpose, 35840B
  __shared__ float b3eff[HIDN];                   // bm1 + be2 @ Wm1

  const int tid = threadIdx.x;
  const int wv  = tid >> 6;
  const int ln  = tid & 63;
  const int q   = ln >> 4;
  const int c16 = ln & 15;

  const float sg    = 1.f / (1.f + expf(-alphap[0]));
  const float scale = dir ? (1.f - sg) : sg;

  {  // stage weights with k-permutation (coalesced over n)
    const float* Ws[3] = {We2, Wm1, Wm2};
    for (int m = 0; m < 3; ++m) {
      const float s = (m == 2) ? scale : 1.f;
      const float* W = Ws[m];
      for (int p = tid; p < HIDN * HIDN; p += 512) {
        int n = p & (HIDN - 1), k = p >> 7;
        wt[m][swz(n, k)] = f2bf(W[nmap(k) * HIDN + n] * s);
      }
    }
    for (int n = tid; n < HIDN; n += 512) {  // fold be2 into stage-3 bias
      float acc = bm1[n];
      for (int k = 0; k < HIDN; ++k) acc += be2[k] * Wm1[k * HIDN + n];
      b3eff[n] = acc;
    }
  }
  __syncthreads();

  // We1^T A-fragments in registers: fw1[cb][j] = We1[(q*8+j)*128 + cb*16+c16]
  bf16x8 fw1[8];
#pragma unroll
  for (int cb = 0; cb < 8; ++cb)
#pragma unroll
    for (int j = 0; j < 8; ++j)
      fw1[cb][j] = (short)f2bf(We1[(q * 8 + j) * HIDN + cb * 16 + c16]);

  // biases, bf16-pair-packed in registers: acc slot [cb][j] is feature n = 16cb+4q+j
  unsigned int vbA[8][2], vbC[8][2], vbD[8][2];
#pragma unroll
  for (int cb = 0; cb < 8; ++cb) {
    int o = cb * 16 + q * 4;
    vbA[cb][0] = pk2c(be1[o], be1[o + 1]);
    vbA[cb][1] = pk2c(be1[o + 2], be1[o + 3]);
    vbC[cb][0] = pk2c(b3eff[o], b3eff[o + 1]);
    vbC[cb][1] = pk2c(b3eff[o + 2], b3eff[o + 3]);
    vbD[cb][0] = pk2c(bm2[o] * scale, bm2[o + 1] * scale);
    vbD[cb][1] = pk2c(bm2[o + 2] * scale, bm2[o + 3] * scale);
  }

  for (int t = blockIdx.x; t < NT; t += GRID_MAIN) {
    const int e0w = t * TILE + wv * 32;
    const int e_  = e0w + c16;

    f32x4 e0a = *reinterpret_cast<const f32x4*>(&ea[(size_t)e_ * EDIMN + q * 8]);
    f32x4 e0b = *reinterpret_cast<const f32x4*>(&ea[(size_t)e_ * EDIMN + q * 8 + 4]);
    f32x4 e1a = *reinterpret_cast<const f32x4*>(&ea[(size_t)(e_ + 16) * EDIMN + q * 8]);
    f32x4 e1b = *reinterpret_cast<const f32x4*>(&ea[(size_t)(e_ + 16) * EDIMN + q * 8 + 4]);
    const int gi0 = gidx[e_], gi1 = gidx[e_ + 16];

    // scatter indices for the epilogue's row orientation (rows r = 16mb+4q+j)
    int sir[2][4];
#pragma unroll
    for (int mb = 0; mb < 2; ++mb)
#pragma unroll
      for (int j = 0; j < 4; ++j)
        sir[mb][j] = sidx[e0w + 16 * mb + 4 * q + j];

    // x-gather for stage-2 acc init
    f32x4 xg0[8], xg1[8];
#pragma unroll
    for (int cb = 0; cb < 8; ++cb) {
      xg0[cb] = *reinterpret_cast<const f32x4*>(&x[(size_t)gi0 * HIDN + cb * 16 + q * 4]);
      xg1[cb] = *reinterpret_cast<const f32x4*>(&x[(size_t)gi1 * HIDN + cb * 16 + q * 4]);
    }

    f32x4 A0[8], A1[8];
    bf16x8 B0[4], B1[4];

    // ---- stage 1: relu(ea @ We1 + be1)
    {
      bf16x8 E0, E1;
      E0[0] = (short)f2bf(e0a[0]); E0[1] = (short)f2bf(e0a[1]);
      E0[2] = (short)f2bf(e0a[2]); E0[3] = (short)f2bf(e0a[3]);
      E0[4] = (short)f2bf(e0b[0]); E0[5] = (short)f2bf(e0b[1]);
      E0[6] = (short)f2bf(e0b[2]); E0[7] = (short)f2bf(e0b[3]);
      E1[0] = (short)f2bf(e1a[0]); E1[1] = (short)f2bf(e1a[1]);
      E1[2] = (short)f2bf(e1a[2]); E1[3] = (short)f2bf(e1a[3]);
      E1[4] = (short)f2bf(e1b[0]); E1[5] = (short)f2bf(e1b[1]);
      E1[6] = (short)f2bf(e1b[2]); E1[7] = (short)f2bf(e1b[3]);
#pragma unroll
      for (int cb = 0; cb < 8; ++cb) {
        A0[cb] = bini(vbA[cb][0], vbA[cb][1]);
        A1[cb] = A0[cb];
      }
#pragma unroll
      for (int cb = 0; cb < 8; ++cb) {
        A0[cb] = __builtin_amdgcn_mfma_f32_16x16x32_bf16(fw1[cb], E0, A0[cb], 0, 0, 0);
        A1[cb] = __builtin_amdgcn_mfma_f32_16x16x32_bf16(fw1[cb], E1, A1[cb], 0, 0, 0);
      }
      packB<true>(A0, B0);
      packB<true>(A1, B1);
    }

    // ---- stage 2: Y1 @ We2 + x[g]  (be2 folded into stage-3 bias)
#pragma unroll
    for (int cb = 0; cb < 8; ++cb) { A0[cb] = xg0[cb]; A1[cb] = xg1[cb]; }
    mmT(&wt[0][0], A0, A1, B0, B1, c16, q);
    packB<false>(A0, B0);
    packB<false>(A1, B1);

    // ---- stage 3: relu(. @ Wm1 + b3eff)
#pragma unroll
    for (int cb = 0; cb < 8; ++cb) {
      A0[cb] = bini(vbC[cb][0], vbC[cb][1]);
      A1[cb] = A0[cb];
    }
    mmT(&wt[1][0], A0, A1, B0, B1, c16, q);
    packB<true>(A0, B0);
    packB<true>(A1, B1);

    // ---- stage 4: . @ (Wm2*scale) + bm2*scale
#pragma unroll
    for (int cb = 0; cb < 8; ++cb) {
      A0[cb] = bini(vbD[cb][0], vbD[cb][1]);
      A1[cb] = A0[cb];
    }
    mmT(&wt[2][0], A0, A1, B0, B1, c16, q);

    // ---- epilogue: per-wave LDS transpose -> full-line atomics
    // 4 passes of 32 feature-cols; storage col perm: feature 16c+4q+j stored at 16c+q+4j
#pragma unroll
    for (int p = 0; p < 4; ++p) {
#pragma unroll
      for (int cb2 = 0; cb2 < 2; ++cb2) {
        const int cb = 2 * p + cb2;
#pragma unroll
        for (int j = 0; j < 4; ++j) {
          stg[wv][c16][16 * cb2 + q + 4 * j]      = A0[cb][j];
          stg[wv][c16 + 16][16 * cb2 + q + 4 * j] = A1[cb][j];
        }
      }
      const int ca = c16 >> 2, cbt = c16 & 3;      // read perm: col C=16k+c16 -> 16k+4*cbt+ca
#pragma unroll
      for (int mb = 0; mb < 2; ++mb)
#pragma unroll
        for (int j = 0; j < 4; ++j) {
          const int r = 16 * mb + 4 * q + j;
          float v0 = stg[wv][r][4 * cbt + ca];
          float v1 = stg[wv][r][16 + 4 * cbt + ca];
          float* po = out + (size_t)sir[mb][j] * HIDN + 32 * p + c16;
          unsafeAtomicAdd(po, v0);
          unsafeAtomicAdd(po + 16, v1);
        }
    }
  }
}

extern "C" void kernel_launch(void* const* d_in, const int* in_sizes, int n_in,
                              void* d_out, int out_size, void* d_ws, size_t ws_size,
                              hipStream_t stream) {
  const float* x     = (const float*)d_in[0];
  const int*   ei    = (const int*)d_in[1];
  const float* ea    = (const float*)d_in[2];
  const float* alpha = (const float*)d_in[3];
  const float* fWe1 = (const float*)d_in[4],  *fbe1 = (const float*)d_in[5];
  const float* fWe2 = (const float*)d_in[6],  *fbe2 = (const float*)d_in[7];
  const float* fWm1 = (const float*)d_in[8],  *fbm1 = (const float*)d_in[9];
  const float* fWm2 = (const float*)d_in[10], *fbm2 = (const float*)d_in[11];
  const float* bWe1 = (const float*)d_in[12], *bbe1 = (const float*)d_in[13];
  const float* bWe2 = (const float*)d_in[14], *bbe2 = (const float*)d_in[15];
  const float* bWm1 = (const float*)d_in[16], *bbm1 = (const float*)d_in[17];
  const float* bWm2 = (const float*)d_in[18], *bbm2 = (const float*)d_in[19];
  float* out = (float*)d_out;

  int* flag = (int*)d_ws;
  int* idx  = (int*)((char*)d_ws + 256);   // 2*E int32
  int* srcI = idx;
  int* dstI = idx + E_EDGES;

  hipMemsetAsync(d_out, 0, (size_t)out_size * sizeof(float), stream);
  k_detect<<<1, 256, 0, stream>>>(ei, flag);
  k_norm<<<2048, 256, 0, stream>>>(ei, flag, idx);

  // forward: gather x[src], scatter to dst, weight sigma(alpha)
  k_conv<<<GRID_MAIN, 512, 0, stream>>>(x, ea, srcI, dstI,
                                        fWe1, fbe1, fWe2, fbe2, fWm1, fbm1, fWm2, fbm2,
                                        alpha, 0, out);
  // backward: gather x[dst], scatter to src, weight 1-sigma(alpha)
  k_conv<<<GRID_MAIN, 512, 0, stream>>>(x, ea, dstI, srcI,
                                        bWe1, bbe1, bWe2, bbe2, bWm1, bbm1, bWm2, bbm2,
                                        alpha, 1, out);
}

// Round 7
// 1187.171 us; speedup vs baseline: 2.6710x; 1.1868x over previous
//
#include <hip/hip_runtime.h>

#define E_EDGES   800000
#define HIDN      128
#define EDIMN     32
#define TILE      256                 // edges per block-iteration (8 waves x 32)
#define NT        (E_EDGES / TILE)    // 3125
#define GRID_MAIN 256
#define STR       35                  // stg row stride (f32): odd-ish -> rows spread banks

typedef __attribute__((ext_vector_type(8))) short bf16x8;
typedef __attribute__((ext_vector_type(4))) float f32x4;

static __device__ __forceinline__ unsigned short f2bf(float f) {
  unsigned int u = __float_as_uint(f);
  u += 0x7fffu + ((u >> 16) & 1u);
  return (unsigned short)(u >> 16);
}
static __device__ __forceinline__ int swz(int row, int kElem) {
  return row * HIDN + (kElem ^ ((row & 7) << 3));
}
static __device__ __forceinline__ int swz32(int row, int kElem) {
  return row * EDIMN + (kElem ^ ((row & 3) << 3));
}
// k-permutation: hardware slot k_hw holds logical k = nmap(k_hw) (bit permutation, bijective)
static __device__ __forceinline__ int nmap(int k) {
  return ((k >> 5) << 5) | (((k & 7) >> 2) << 4) | (((k >> 3) & 3) << 2) | (k & 3);
}

template <bool RELU>
static __device__ __forceinline__ void packB(const f32x4* acc, bf16x8* B) {
#pragma unroll
  for (int ks = 0; ks < 4; ++ks) {
    f32x4 a = acc[2 * ks], b = acc[2 * ks + 1];
    if (RELU) {
#pragma unroll
      for (int j = 0; j < 4; ++j) { a[j] = fmaxf(a[j], 0.f); b[j] = fmaxf(b[j], 0.f); }
    }
    bf16x8 v;
    v[0] = (short)f2bf(a[0]); v[1] = (short)f2bf(a[1]);
    v[2] = (short)f2bf(a[2]); v[3] = (short)f2bf(a[3]);
    v[4] = (short)f2bf(b[0]); v[5] = (short)f2bf(b[1]);
    v[6] = (short)f2bf(b[2]); v[7] = (short)f2bf(b[3]);
    B[ks] = v;
  }
}

static __device__ __forceinline__ void mmT(const unsigned short* W, f32x4* a0, f32x4* a1,
                                           const bf16x8* B0, const bf16x8* B1,
                                           int c16, int q) {
#pragma unroll
  for (int cb = 0; cb < 8; ++cb) {
#pragma unroll
    for (int ks = 0; ks < 4; ++ks) {
      bf16x8 w = *reinterpret_cast<const bf16x8*>(&W[swz(cb * 16 + c16, ks * 32 + q * 8)]);
      a0[cb] = __builtin_amdgcn_mfma_f32_16x16x32_bf16(w, B0[ks], a0[cb], 0, 0, 0);
      a1[cb] = __builtin_amdgcn_mfma_f32_16x16x32_bf16(w, B1[ks], a1[cb], 0, 0, 0);
    }
  }
}

__global__ void k_detect(const int* __restrict__ ei, int* __restrict__ flag) {
  __shared__ int nz;
  if (threadIdx.x == 0) nz = 0;
  __syncthreads();
  if (ei[2 * threadIdx.x + 1] != 0) atomicAdd(&nz, 1);
  __syncthreads();
  if (threadIdx.x == 0) flag[0] = (nz == 0) ? 1 : 0;   // 1 => int64
}

__global__ void k_norm(const int* __restrict__ ei, const int* __restrict__ flag,
                       int* __restrict__ idx) {
  const int stride = gridDim.x * blockDim.x;
  const int w = flag[0];
  for (int i = blockIdx.x * blockDim.x + threadIdx.x; i < 2 * E_EDGES; i += stride)
    idx[i] = w ? ei[2 * i] : ei[i];
}

__launch_bounds__(512)
__attribute__((amdgpu_waves_per_eu(2)))
__global__ void k_conv(const float* __restrict__ x, const float* __restrict__ ea,
                       const int* __restrict__ gidx, const int* __restrict__ sidx,
                       const float* __restrict__ We1, const float* __restrict__ be1,
                       const float* __restrict__ We2, const float* __restrict__ be2,
                       const float* __restrict__ Wm1, const float* __restrict__ bm1,
                       const float* __restrict__ Wm2, const float* __restrict__ bm2,
                       const float* __restrict__ alphap, int dir,
                       float* __restrict__ out) {
  __shared__ unsigned short wt[3][HIDN * HIDN];   // We2,Wm1,Wm2*scale; [n][k_hw] swizzled, 96KB
  __shared__ unsigned short w1[HIDN * EDIMN];     // We1^T [n][k] swizzled, 8KB
  __shared__ float stg[8][32][STR];               // per-wave epilogue transpose, 35840B
  __shared__ float b1l[HIDN];                     // be1
  __shared__ float b3l[HIDN];                     // bm1 + be2 @ Wm1
  __shared__ float b4l[HIDN];                     // bm2 * scale

  const int tid = threadIdx.x;
  const int wv  = tid >> 6;
  const int ln  = tid & 63;
  const int q   = ln >> 4;
  const int c16 = ln & 15;

  const float sg    = 1.f / (1.f + expf(-alphap[0]));
  const float scale = dir ? (1.f - sg) : sg;

  {  // stage weights with k-permutation (coalesced over n)
    const float* Ws[3] = {We2, Wm1, Wm2};
    for (int m = 0; m < 3; ++m) {
      const float s = (m == 2) ? scale : 1.f;
      const float* W = Ws[m];
      for (int p = tid; p < HIDN * HIDN; p += 512) {
        int n = p & (HIDN - 1), k = p >> 7;
        wt[m][swz(n, k)] = f2bf(W[nmap(k) * HIDN + n] * s);
      }
    }
    for (int p = tid; p < HIDN * EDIMN; p += 512) {
      int n = p & (HIDN - 1), k = p >> 7;
      w1[swz32(n, k)] = f2bf(We1[k * HIDN + n]);
    }
    for (int n = tid; n < HIDN; n += 512) {
      b1l[n] = be1[n];
      b4l[n] = bm2[n] * scale;
      float acc = bm1[n];                          // fold be2 into stage-3 bias
      for (int k = 0; k < HIDN; ++k) acc += be2[k] * Wm1[k * HIDN + n];
      b3l[n] = acc;
    }
  }
  __syncthreads();

  const int o4 = q * 4;   // acc slot [cb][j] is feature n = 16cb + 4q + j

  for (int t = blockIdx.x; t < NT; t += GRID_MAIN) {
    const int e0w = t * TILE + wv * 32;
    const int e_  = e0w + c16;

    f32x4 e0a = *reinterpret_cast<const f32x4*>(&ea[(size_t)e_ * EDIMN + q * 8]);
    f32x4 e0b = *reinterpret_cast<const f32x4*>(&ea[(size_t)e_ * EDIMN + q * 8 + 4]);
    f32x4 e1a = *reinterpret_cast<const f32x4*>(&ea[(size_t)(e_ + 16) * EDIMN + q * 8]);
    f32x4 e1b = *reinterpret_cast<const f32x4*>(&ea[(size_t)(e_ + 16) * EDIMN + q * 8 + 4]);
    const int gi0 = gidx[e_], gi1 = gidx[e_ + 16];

    // scatter indices for the epilogue's row orientation (rows r = 16mb+4q+j)
    int sir[2][4];
#pragma unroll
    for (int mb = 0; mb < 2; ++mb)
#pragma unroll
      for (int j = 0; j < 4; ++j)
        sir[mb][j] = sidx[e0w + 16 * mb + 4 * q + j];

    f32x4 A0[8], A1[8];
    bf16x8 B0[4], B1[4];

    // ---- stage 1: relu(ea @ We1 + be1)
    {
      bf16x8 E0, E1;
      E0[0] = (short)f2bf(e0a[0]); E0[1] = (short)f2bf(e0a[1]);
      E0[2] = (short)f2bf(e0a[2]); E0[3] = (short)f2bf(e0a[3]);
      E0[4] = (short)f2bf(e0b[0]); E0[5] = (short)f2bf(e0b[1]);
      E0[6] = (short)f2bf(e0b[2]); E0[7] = (short)f2bf(e0b[3]);
      E1[0] = (short)f2bf(e1a[0]); E1[1] = (short)f2bf(e1a[1]);
      E1[2] = (short)f2bf(e1a[2]); E1[3] = (short)f2bf(e1a[3]);
      E1[4] = (short)f2bf(e1b[0]); E1[5] = (short)f2bf(e1b[1]);
      E1[6] = (short)f2bf(e1b[2]); E1[7] = (short)f2bf(e1b[3]);
#pragma unroll
      for (int cb = 0; cb < 8; ++cb) {
        A0[cb] = *reinterpret_cast<const f32x4*>(&b1l[cb * 16 + o4]);   // LDS broadcast
        A1[cb] = A0[cb];
      }
#pragma unroll
      for (int cb = 0; cb < 8; ++cb) {
        bf16x8 w = *reinterpret_cast<const bf16x8*>(&w1[swz32(cb * 16 + c16, q * 8)]);
        A0[cb] = __builtin_amdgcn_mfma_f32_16x16x32_bf16(w, E0, A0[cb], 0, 0, 0);
        A1[cb] = __builtin_amdgcn_mfma_f32_16x16x32_bf16(w, E1, A1[cb], 0, 0, 0);
      }
      packB<true>(A0, B0);
      packB<true>(A1, B1);
    }

    // ---- stage 2: Y1 @ We2 + x[g]  (x loaded straight into the accumulator)
#pragma unroll
    for (int cb = 0; cb < 8; ++cb) {
      A0[cb] = *reinterpret_cast<const f32x4*>(&x[(size_t)gi0 * HIDN + cb * 16 + o4]);
      A1[cb] = *reinterpret_cast<const f32x4*>(&x[(size_t)gi1 * HIDN + cb * 16 + o4]);
    }
    mmT(&wt[0][0], A0, A1, B0, B1, c16, q);
    packB<false>(A0, B0);
    packB<false>(A1, B1);

    // ---- stage 3: relu(. @ Wm1 + b3eff)
#pragma unroll
    for (int cb = 0; cb < 8; ++cb) {
      A0[cb] = *reinterpret_cast<const f32x4*>(&b3l[cb * 16 + o4]);
      A1[cb] = A0[cb];
    }
    mmT(&wt[1][0], A0, A1, B0, B1, c16, q);
    packB<true>(A0, B0);
    packB<true>(A1, B1);

    // ---- stage 4: . @ (Wm2*scale) + bm2*scale
#pragma unroll
    for (int cb = 0; cb < 8; ++cb) {
      A0[cb] = *reinterpret_cast<const f32x4*>(&b4l[cb * 16 + o4]);
      A1[cb] = A0[cb];
    }
    mmT(&wt[2][0], A0, A1, B0, B1, c16, q);

    // ---- epilogue: per-wave LDS transpose -> full-line atomics
    // 4 passes of 32 feature-cols; storage col perm: feature 16c+4q+j stored at 16c+q+4j
#pragma unroll
    for (int p = 0; p < 4; ++p) {
#pragma unroll
      for (int cb2 = 0; cb2 < 2; ++cb2) {
        const int cb = 2 * p + cb2;
#pragma unroll
        for (int j = 0; j < 4; ++j) {
          stg[wv][c16][16 * cb2 + q + 4 * j]      = A0[cb][j];
          stg[wv][c16 + 16][16 * cb2 + q + 4 * j] = A1[cb][j];
        }
      }
      const int ca = c16 >> 2, cbt = c16 & 3;      // read perm: col C=16k+c16 -> 16k+4*cbt+ca
#pragma unroll
      for (int mb = 0; mb < 2; ++mb)
#pragma unroll
        for (int j = 0; j < 4; ++j) {
          const int r = 16 * mb + 4 * q + j;
          float v0 = stg[wv][r][4 * cbt + ca];
          float v1 = stg[wv][r][16 + 4 * cbt + ca];
          float* po = out + (size_t)sir[mb][j] * HIDN + 32 * p + c16;
          unsafeAtomicAdd(po, v0);
          unsafeAtomicAdd(po + 16, v1);
        }
    }
  }
}

extern "C" void kernel_launch(void* const* d_in, const int* in_sizes, int n_in,
                              void* d_out, int out_size, void* d_ws, size_t ws_size,
                              hipStream_t stream) {
  const float* x     = (const float*)d_in[0];
  const int*   ei    = (const int*)d_in[1];
  const float* ea    = (const float*)d_in[2];
  const float* alpha = (const float*)d_in[3];
  const float* fWe1 = (const float*)d_in[4],  *fbe1 = (const float*)d_in[5];
  const float* fWe2 = (const float*)d_in[6],  *fbe2 = (const float*)d_in[7];
  const float* fWm1 = (const float*)d_in[8],  *fbm1 = (const float*)d_in[9];
  const float* fWm2 = (const float*)d_in[10], *fbm2 = (const float*)d_in[11];
  const float* bWe1 = (const float*)d_in[12], *bbe1 = (const float*)d_in[13];
  const float* bWe2 = (const float*)d_in[14], *bbe2 = (const float*)d_in[15];
  const float* bWm1 = (const float*)d_in[16], *bbm1 = (const float*)d_in[17];
  const float* bWm2 = (const float*)d_in[18], *bbm2 = (const float*)d_in[19];
  float* out = (float*)d_out;

  int* flag = (int*)d_ws;
  int* idx  = (int*)((char*)d_ws + 256);   // 2*E int32
  int* srcI = idx;
  int* dstI = idx + E_EDGES;

  hipMemsetAsync(d_out, 0, (size_t)out_size * sizeof(float), stream);
  k_detect<<<1, 256, 0, stream>>>(ei, flag);
  k_norm<<<2048, 256, 0, stream>>>(ei, flag, idx);

  // forward: gather x[src], scatter to dst, weight sigma(alpha)
  k_conv<<<GRID_MAIN, 512, 0, stream>>>(x, ea, srcI, dstI,
                                        fWe1, fbe1, fWe2, fbe2, fWm1, fbm1, fWm2, fbm2,
                                        alpha, 0, out);
  // backward: gather x[dst], scatter to src, weight 1-sigma(alpha)
  k_conv<<<GRID_MAIN, 512, 0, stream>>>(x, ea, dstI, srcI,
                                        bWe1, bbe1, bWe2, bbe2, bWm1, bbm1, bWm2, bbm2,
                                        alpha, 1, out);
}